// Round 12
// baseline (242.096 us; speedup 1.0000x reference)
//
#include <hip/hip_runtime.h>

#define T_SEQ 4096
#define NBATCH 4
#define EMB 1024
#define HS 64
#define BT (NBATCH * T_SEQ)   // 16384 token rows

typedef float f32x4 __attribute__((ext_vector_type(4)));
typedef short s16x8 __attribute__((ext_vector_type(8)));

__device__ __forceinline__ unsigned short f2bf(float x) {  // RNE fp32->bf16
  union { float f; unsigned u; } c; c.f = x;
  unsigned r = c.u + 0x7FFF + ((c.u >> 16) & 1);
  return (unsigned short)(r >> 16);
}
__device__ __forceinline__ float bf2f(unsigned short h) {
  union { unsigned u; float f; } c; c.u = ((unsigned)h) << 16;
  return c.f;
}
__device__ __forceinline__ void cvt8(float4 a0, float4 a1, s16x8& hi, s16x8& lo) {
  float xv[8] = {a0.x, a0.y, a0.z, a0.w, a1.x, a1.y, a1.z, a1.w};
#pragma unroll
  for (int j = 0; j < 8; ++j) {
    unsigned short h = f2bf(xv[j]);
    hi[j] = (short)h;
    lo[j] = (short)f2bf(xv[j] - bf2f(h));
  }
}

// ---------------- Kernel 0: W -> W^T hi/lo bf16 (R8 verbatim) ------------
__global__ __launch_bounds__(256) void wconv(
    const float* __restrict__ Wq, const float* __restrict__ Wk,
    const float* __restrict__ Wv, unsigned short* __restrict__ wt_hi,
    unsigned short* __restrict__ wt_lo) {
  const int n3 = blockIdx.x;
  const int which = n3 >> 6, n = n3 & 63;
  const float* W = (which == 0) ? Wq : (which == 1) ? Wk : Wv;
#pragma unroll
  for (int i = 0; i < 4; ++i) {
    int k = i * 256 + threadIdx.x;
    float x = W[(size_t)k * HS + n];
    unsigned short h = f2bf(x);
    wt_hi[(size_t)n3 * EMB + k] = h;
    wt_lo[(size_t)n3 * EMB + k] = f2bf(x - bf2f(h));
  }
}

// ---------------- Kernel 1: QKV — in-block wave K-split, 16-iter chain ----
// grid 256, block 1024 = 16 waves: w = mg*4 + ng2*2 + ks.
//   mg (0..3): 16-token row group; ng2 (0..1): 96-col group (6 nt);
//   ks (0..1): K half [ks*512, ks*512+512). Chain = 16 iters (was 32).
// LDS (aliased char array, 55296 B):
//   Bhi0 @0, Blo0 @13824, Bhi1 @27648, Blo1 @41472 (each 192 rows x 36 sh)
//   Red  @0 (fp32, tok stride 196 words, 50176 B) -- used AFTER the loop.
// Staging/iter: 3072 uint4 (4 bufs x 768), 3 NAMED stores/thread:
//   g0=t:      t<768 -> Bhi0[t]       else Blo0[t-768]   (Blo0 [0,256))
//   g1=1024+t: t<512 -> Blo0[256+t]   else Bhi1[t-512]   (Bhi1 [0,512))
//   g2=2048+t: t<256 -> Bhi1[512+t]   else Blo1[t-256]   (Blo1 [0,768))
//   => Bhi0/Blo0/Bhi1/Blo1 each exactly [0,768). Full, disjoint.
__global__ __launch_bounds__(1024) void qkv_mfma(
    const float* __restrict__ inp, const unsigned short* __restrict__ wt_hi,
    const unsigned short* __restrict__ wt_lo, float* __restrict__ qf,
    unsigned short* __restrict__ khi, unsigned short* __restrict__ klo,
    unsigned short* __restrict__ vtb) {
  __shared__ __align__(16) char smem[55296];
  unsigned short* Bs = (unsigned short*)smem;  // 4 x 6912-short regions
  float* Red = (float*)smem;

  const int t = threadIdx.x, lane = t & 63, w = t >> 6;
  const int m = lane & 15, quad = lane >> 4;
  const int mg = w >> 2, ng2 = (w >> 1) & 1, ks = w & 1;
  const int tok0 = blockIdx.x * 64;
  const int arow = tok0 + mg * 16 + m;

  f32x4 acc[6];
#pragma unroll
  for (int nt = 0; nt < 6; ++nt) acc[nt] = (f32x4){0.f, 0.f, 0.f, 0.f};

  // staging slots (loop-invariant, named)
  const int buf0 = (t < 768) ? 0 : 1;
  const int idx0 = (t < 768) ? t : t - 768;
  const int buf1 = (t < 512) ? 1 : 2;
  const int idx1 = (t < 512) ? (256 + t) : (t - 512);
  const int buf2 = (t < 256) ? 2 : 3;
  const int idx2 = (t < 256) ? (512 + t) : (t - 256);
  const unsigned short* src0 = (buf0 & 1) ? wt_lo : wt_hi;
  const unsigned short* src1 = (buf1 & 1) ? wt_lo : wt_hi;
  const unsigned short* src2 = (buf2 & 1) ? wt_lo : wt_hi;
  const size_t off0 = (size_t)(idx0 >> 2) * EMB + (buf0 >> 1) * 512 + (idx0 & 3) * 8;
  const size_t off1 = (size_t)(idx1 >> 2) * EMB + (buf1 >> 1) * 512 + (idx1 & 3) * 8;
  const size_t off2 = (size_t)(idx2 >> 2) * EMB + (buf2 >> 1) * 512 + (idx2 & 3) * 8;
  unsigned short* lds0 = Bs + buf0 * 6912 + (idx0 >> 2) * 36 + (idx0 & 3) * 8;
  unsigned short* lds1 = Bs + buf1 * 6912 + (idx1 >> 2) * 36 + (idx1 & 3) * 8;
  unsigned short* lds2 = Bs + buf2 * 6912 + (idx2 >> 2) * 36 + (idx2 & 3) * 8;

  // this wave's B-frag base (its ks half)
  const unsigned short* Bhi_w = Bs + ks * 13824;          // in shorts: ks*2*6912
  const unsigned short* Blo_w = Bs + 6912 + ks * 13824;

  uint4 bpa, bpb, bpc;
  float4 apre0, apre1;
  bpa = *(const uint4*)&src0[off0];
  bpb = *(const uint4*)&src1[off1];
  bpc = *(const uint4*)&src2[off2];
  {
    const float* ap = &inp[(size_t)arow * EMB + ks * 512 + quad * 8];
    apre0 = *(const float4*)ap;
    apre1 = *(const float4*)(ap + 4);
  }

  for (int kc = 0; kc < 16; ++kc) {
    const int k0n = (kc + 1) * 32;
    __syncthreads();  // previous iteration's B readers done
    *(uint4*)lds0 = bpa;
    *(uint4*)lds1 = bpb;
    *(uint4*)lds2 = bpc;
    __syncthreads();

    s16x8 ah, al;
    cvt8(apre0, apre1, ah, al);

    if (kc < 15) {  // 1-iter lookahead
      bpa = *(const uint4*)&src0[off0 + k0n];
      bpb = *(const uint4*)&src1[off1 + k0n];
      bpc = *(const uint4*)&src2[off2 + k0n];
      const float* ap = &inp[(size_t)arow * EMB + ks * 512 + k0n + quad * 8];
      apre0 = *(const float4*)ap;
      apre1 = *(const float4*)(ap + 4);
    }

#pragma unroll
    for (int nt = 0; nt < 6; ++nt) {
      int n3 = ng2 * 96 + nt * 16 + m;
      s16x8 bh = *(const s16x8*)&Bhi_w[n3 * 36 + quad * 8];
      s16x8 bl = *(const s16x8*)&Blo_w[n3 * 36 + quad * 8];
      acc[nt] = __builtin_amdgcn_mfma_f32_16x16x32_bf16(ah, bh, acc[nt], 0, 0, 0);
      acc[nt] = __builtin_amdgcn_mfma_f32_16x16x32_bf16(ah, bl, acc[nt], 0, 0, 0);
      acc[nt] = __builtin_amdgcn_mfma_f32_16x16x32_bf16(al, bh, acc[nt], 0, 0, 0);
    }
  }

  // cross-ks reduce through LDS (aliases B buffers -- barrier first)
  __syncthreads();
  if (ks == 1) {
#pragma unroll
    for (int nt = 0; nt < 6; ++nt) {
      int col = ng2 * 96 + nt * 16 + m;
#pragma unroll
      for (int r = 0; r < 4; ++r) {
        int tok = mg * 16 + quad * 4 + r;  // block-local
        Red[tok * 196 + col] = acc[nt][r];
      }
    }
  }
  __syncthreads();
  if (ks == 0) {
#pragma unroll
    for (int nt = 0; nt < 6; ++nt) {
      int col = ng2 * 96 + nt * 16 + m;
      int which = col >> 6, c3 = col & 63;
#pragma unroll
      for (int r = 0; r < 4; ++r) {
        int tokl = mg * 16 + quad * 4 + r;
        float val = acc[nt][r] + Red[tokl * 196 + col];
        int tok = tok0 + tokl;
        if (which == 0) {
          qf[(size_t)tok * HS + c3] = val;
        } else if (which == 1) {
          unsigned short h = f2bf(val);
          khi[(size_t)tok * HS + c3] = h;
          klo[(size_t)tok * HS + c3] = f2bf(val - bf2f(h));
        } else {
          vtb[(size_t)(tok >> 6) * 4096 + (size_t)c3 * 64 + (tok & 63)] = f2bf(val);
        }
      }
    }
  }
}

// ---------------- Kernel 2a: flash partials (R9/R11 verbatim) -------------
__global__ __launch_bounds__(256) void attn_part(
    const float* __restrict__ q, const unsigned short* __restrict__ khi,
    const unsigned short* __restrict__ klo, const unsigned short* __restrict__ vt,
    unsigned short* __restrict__ partO, float* __restrict__ partML) {
  __shared__ unsigned short Khi_s[64 * 72];
  __shared__ unsigned short Klo_s[64 * 72];
  __shared__ unsigned short Vt_s[64 * 72];
  __shared__ unsigned short P_s[4 * 16 * 72];
  const int t = threadIdx.x;
  const int lane = t & 63, w = t >> 6;
  const int m = lane & 15, quad = lane >> 4;

  int u = blockIdx.x;
  const int b = u / 160;
  u -= b * 160;
  int qtile = 0, c = 0;
  {
    int acc2 = 0;
    for (int qq = 0; qq < 64; ++qq) {
      int ncq = (qq >> 4) + 1;
      if (u < acc2 + ncq) { qtile = qq; c = u - acc2; break; }
      acc2 += ncq;
    }
  }
  const int kt0 = c * 16;
  const int kt1 = (kt0 + 16 < qtile + 1) ? kt0 + 16 : qtile + 1;

  const size_t qrow0 = (size_t)b * T_SEQ + (size_t)qtile * 64;
  const size_t krowbase = (size_t)b * T_SEQ;
  const int q_loc = w * 16 + m;

  s16x8 qh[2], ql[2];
#pragma unroll
  for (int cc = 0; cc < 2; ++cc) {
    const float* qp = &q[(qrow0 + q_loc) * HS + cc * 32 + quad * 8];
    cvt8(*(const float4*)qp, *(const float4*)(qp + 4), qh[cc], ql[cc]);
  }

  float l_st = 0.f;
  f32x4 o[4];
#pragma unroll
  for (int hb = 0; hb < 4; ++hb) o[hb] = (f32x4){0.f, 0.f, 0.f, 0.f};

  const int r0 = t >> 3, ch0 = t & 7;
  const int r1 = (256 + t) >> 3, ch1 = t & 7;

  uint4 pk0h, pk0l, pv0, pk1h, pk1l, pv1;
  {
    size_t g0 = (krowbase + (size_t)kt0 * 64 + r0) * HS + ch0 * 8;
    size_t g1 = (krowbase + (size_t)kt0 * 64 + r1) * HS + ch1 * 8;
    pk0h = *(const uint4*)&khi[g0]; pk0l = *(const uint4*)&klo[g0];
    pk1h = *(const uint4*)&khi[g1]; pk1l = *(const uint4*)&klo[g1];
    size_t v0 = (size_t)(b * 64 + kt0) * 4096 + (size_t)r0 * 64 + ch0 * 8;
    size_t v1 = (size_t)(b * 64 + kt0) * 4096 + (size_t)r1 * 64 + ch1 * 8;
    pv0 = *(const uint4*)&vt[v0]; pv1 = *(const uint4*)&vt[v1];
  }

  for (int kt = kt0; kt < kt1; ++kt) {
    __syncthreads();
    *(uint4*)&Khi_s[r0 * 72 + ch0 * 8] = pk0h;
    *(uint4*)&Klo_s[r0 * 72 + ch0 * 8] = pk0l;
    *(uint4*)&Vt_s[r0 * 72 + ch0 * 8] = pv0;
    *(uint4*)&Khi_s[r1 * 72 + ch1 * 8] = pk1h;
    *(uint4*)&Klo_s[r1 * 72 + ch1 * 8] = pk1l;
    *(uint4*)&Vt_s[r1 * 72 + ch1 * 8] = pv1;
    __syncthreads();

    if (kt + 1 < kt1) {
      size_t g0 = (krowbase + (size_t)(kt + 1) * 64 + r0) * HS + ch0 * 8;
      size_t g1 = (krowbase + (size_t)(kt + 1) * 64 + r1) * HS + ch1 * 8;
      pk0h = *(const uint4*)&khi[g0]; pk0l = *(const uint4*)&klo[g0];
      pk1h = *(const uint4*)&khi[g1]; pk1l = *(const uint4*)&klo[g1];
      size_t v0 = (size_t)(b * 64 + kt + 1) * 4096 + (size_t)r0 * 64 + ch0 * 8;
      size_t v1 = (size_t)(b * 64 + kt + 1) * 4096 + (size_t)r1 * 64 + ch1 * 8;
      pv0 = *(const uint4*)&vt[v0]; pv1 = *(const uint4*)&vt[v1];
    }

    f32x4 st[4];
#pragma unroll
    for (int cb = 0; cb < 4; ++cb) {
      st[cb] = (f32x4){0.f, 0.f, 0.f, 0.f};
#pragma unroll
      for (int cc = 0; cc < 2; ++cc) {
        s16x8 bh = *(const s16x8*)&Khi_s[(cb * 16 + m) * 72 + cc * 32 + quad * 8];
        s16x8 bl = *(const s16x8*)&Klo_s[(cb * 16 + m) * 72 + cc * 32 + quad * 8];
        st[cb] = __builtin_amdgcn_mfma_f32_16x16x32_bf16(bh, qh[cc], st[cb], 0, 0, 0);
        st[cb] = __builtin_amdgcn_mfma_f32_16x16x32_bf16(bl, qh[cc], st[cb], 0, 0, 0);
        st[cb] = __builtin_amdgcn_mfma_f32_16x16x32_bf16(bh, ql[cc], st[cb], 0, 0, 0);
      }
    }
    if (kt == qtile) {
#pragma unroll
      for (int cb = 0; cb < 4; ++cb)
#pragma unroll
        for (int r = 0; r < 4; ++r)
          if (cb * 16 + quad * 4 + r > q_loc) st[cb][r] = -1e30f;
    }
#pragma unroll
    for (int cb = 0; cb < 4; ++cb)
#pragma unroll
      for (int r = 0; r < 4; ++r) {
        st[cb][r] = __expf(st[cb][r]);
        l_st += st[cb][r];
      }
#pragma unroll
    for (int cb = 0; cb < 4; ++cb) {
      uint2 pk;
      pk.x = (unsigned)f2bf(st[cb][0]) | ((unsigned)f2bf(st[cb][1]) << 16);
      pk.y = (unsigned)f2bf(st[cb][2]) | ((unsigned)f2bf(st[cb][3]) << 16);
      *(uint2*)&P_s[q_loc * 72 + cb * 16 + quad * 4] = pk;
    }
    s16x8 pf[2];
#pragma unroll
    for (int cc = 0; cc < 2; ++cc)
      pf[cc] = *(const s16x8*)&P_s[q_loc * 72 + cc * 32 + quad * 8];
#pragma unroll
    for (int hb = 0; hb < 4; ++hb) {
#pragma unroll
      for (int cc = 0; cc < 2; ++cc) {
        s16x8 vf = *(const s16x8*)&Vt_s[(hb * 16 + m) * 72 + cc * 32 + quad * 8];
        o[hb] = __builtin_amdgcn_mfma_f32_16x16x32_bf16(vf, pf[cc], o[hb], 0, 0, 0);
      }
    }
  }

  l_st += __shfl_xor(l_st, 16, 64);
  l_st += __shfl_xor(l_st, 32, 64);

  const int slot = ((b * 64 + qtile) << 2) + c;
  unsigned short* Op = partO + (size_t)slot * 4096;
#pragma unroll
  for (int hb = 0; hb < 4; ++hb) {
    uint2 pk;
    pk.x = (unsigned)f2bf(o[hb][0]) | ((unsigned)f2bf(o[hb][1]) << 16);
    pk.y = (unsigned)f2bf(o[hb][2]) | ((unsigned)f2bf(o[hb][3]) << 16);
    *(uint2*)&Op[q_loc * 64 + hb * 16 + quad * 4] = pk;
  }
  if (quad == 0) partML[(size_t)slot * 64 + q_loc] = l_st;
}

// ---------------- Kernel 2b: combine = plain sums (flat softmax) ----------
__global__ __launch_bounds__(256) void attn_combine(
    const unsigned short* __restrict__ partO, const float* __restrict__ partML,
    float* __restrict__ out) {
  const int qtile = blockIdx.x, b = blockIdx.y;
  const int t = threadIdx.x;
  const int row = t >> 2, hg = t & 3;
  const int nc = (qtile >> 4) + 1;
  const int slot0 = (b * 64 + qtile) << 2;

  float lsum = 0.f;
  for (int i = 0; i < nc; ++i) lsum += partML[(size_t)(slot0 + i) * 64 + row];
  const float inv = 1.f / (lsum * 8.0f);  // ref divides by sqrt(64) after softmax

  float acc[16];
#pragma unroll
  for (int e = 0; e < 16; ++e) acc[e] = 0.f;
  for (int i = 0; i < nc; ++i) {
    const unsigned short* Op =
        partO + (size_t)(slot0 + i) * 4096 + row * 64 + hg * 16;
    uint4 u0 = *(const uint4*)Op;
    uint4 u1 = *(const uint4*)(Op + 8);
    unsigned uv[8] = {u0.x, u0.y, u0.z, u0.w, u1.x, u1.y, u1.z, u1.w};
#pragma unroll
    for (int e = 0; e < 8; ++e) {
      acc[2 * e] += bf2f((unsigned short)(uv[e] & 0xFFFF));
      acc[2 * e + 1] += bf2f((unsigned short)(uv[e] >> 16));
    }
  }
  float* op = &out[((size_t)b * T_SEQ + (size_t)qtile * 64 + row) * HS + hg * 16];
#pragma unroll
  for (int v = 0; v < 4; ++v) {
    float4 r;
    r.x = acc[4 * v + 0] * inv; r.y = acc[4 * v + 1] * inv;
    r.z = acc[4 * v + 2] * inv; r.w = acc[4 * v + 3] * inv;
    ((float4*)op)[v] = r;
  }
}

extern "C" void kernel_launch(void* const* d_in, const int* in_sizes, int n_in,
                              void* d_out, int out_size, void* d_ws, size_t ws_size,
                              hipStream_t stream) {
  const float* inp = (const float*)d_in[0];
  const float* Wq  = (const float*)d_in[1];
  const float* Wk  = (const float*)d_in[2];
  const float* Wv  = (const float*)d_in[3];
  float* out = (float*)d_out;

  // ws: qf 4MB | khi 2MB | klo 2MB | vt 2MB | wt_hi .375MB | wt_lo .375MB
  //     | partO bf16 8MB | partML 256KB  (~19 MB)
  char* base = (char*)d_ws;
  float* qf = (float*)base;
  unsigned short* khi = (unsigned short*)(base + (size_t)BT * HS * 4);
  unsigned short* klo = khi + (size_t)BT * HS;
  unsigned short* vtb = klo + (size_t)BT * HS;
  unsigned short* wt_hi = vtb + (size_t)BT * HS;
  unsigned short* wt_lo = wt_hi + (size_t)192 * EMB;
  unsigned short* partO = wt_lo + (size_t)192 * EMB;
  float* partML = (float*)(partO + (size_t)1024 * 4096);

  wconv<<<dim3(192), dim3(256), 0, stream>>>(Wq, Wk, Wv, wt_hi, wt_lo);
  qkv_mfma<<<dim3(BT / 64), dim3(1024), 0, stream>>>(inp, wt_hi, wt_lo, qf, khi, klo, vtb);
  attn_part<<<dim3(640), dim3(256), 0, stream>>>(qf, khi, klo, vtb, partO, partML);
  attn_combine<<<dim3(64, NBATCH), dim3(256), 0, stream>>>(partO, partML, out);
}